// Round 9
// baseline (48.487 us; speedup 1.0000x reference)
//
#include <hip/hip_runtime.h>
#include <cmath>

// Single fused kernel, ZERO barriers in the streaming loop.
//
// Math: angles = tanh(x@W^T + b); the fixed 3-layer circuit is a constant
// 16x16 unitary U; the output collapses to an 81x4 tensor A contracted with
// g[9] x h[9] built from sincos(angles). A is rebuilt per block in LDS
// (~2-3us, all 2048 blocks resident & concurrent, hidden under prefetch).
//
// Streaming (the new part): per wave-iteration, each lane loads ONE float4
// of a 4-row group (wave = 1 KB contiguous, perfectly coalesced, exactly
// once). Lane l permanently owns feature slice (l&15)*4..+3, with W
// preloaded into 16 VGPRs. 16 FMA -> partial dots; 4x __shfl_xor
// (masks 1,2,4,8 = in-row DPP, VALU speed, NO LDS, NO barrier) all-reduce
// within each 16-lane group; lane (l&15)==i keeps iteration i's row.
// After 16 iterations each lane owns one of the wave's 64 rows and runs
// the transcendental tail + A-contraction (uniform LDS broadcasts)
// independently. No __syncthreads after prep -> no vmcnt(0) drains ->
// prefetch actually stays in flight (4-deep).

__global__ __launch_bounds__(256)
__attribute__((amdgpu_waves_per_eu(4, 4)))   // 128-VGPR budget: no spill
void qfused_kernel(
    const float* __restrict__ x,    // [B][64]
    const float* __restrict__ Wp,   // [4][64]
    const float* __restrict__ bp,   // [4]
    const float* __restrict__ qw,   // [3][4][2]
    float* __restrict__ out)        // [B][4]
{
  // LDS: A[324] at 0 (16B-aligned), prep scratch after (dead post-prep).
  constexpr int AOF = 0;     // 81 x float4
  constexpr int SRE = 328;   // 16x17
  constexpr int SIM = 600;   // 16x17
  constexpr int MOF = 872;   // 4x16x16
  __shared__ alignas(16) float lds[872 + 1024];   // 7.6 KB

  const int tid  = threadIdx.x;
  const int lane = tid & 63;
  const int q    = lane >> 4;        // row-in-quad (0..3)
  const int f4   = lane & 15;        // owned float4-column (0..15)

  // wave's 64-row window
  const size_t base = ((size_t)blockIdx.x * 4 + (tid >> 6)) * 64;
  // iter i reads float4 at row (base + 4i + q), col f4  ->  xw[64*i]
  const float4* xw = reinterpret_cast<const float4*>(x) +
                     base * 16 + (size_t)q * 16 + f4;

  // ---- 4-deep prefetch; in flight during prep ----
  float4 p0 = xw[0], p1 = xw[64], p2 = xw[128], p3 = xw[192];

  // ---- prep: build A[81][4] at lds[0] (256 thr = 16 cols x 16 amps) ----
  {
    const int col = tid >> 4;
    const int u   = tid & 15;
    lds[SRE + col * 17 + u] = (u == col) ? 1.0f : 0.0f;
    lds[SIM + col * 17 + u] = 0.0f;
    __syncthreads();

#pragma unroll
    for (int l = 0; l < 3; ++l) {
#pragma unroll
      for (int w = 0; w < 4; ++w) {
        const int mask = 8 >> w;     // wire 0 = MSB
        float sh, ch, sh2, ch2;
        __sincosf(0.5f * qw[(l * 4 + w) * 2 + 0], &sh, &ch);    // RY
        __sincosf(0.5f * qw[(l * 4 + w) * 2 + 1], &sh2, &ch2);  // RZ
        const int ua = u & ~mask, ub = u | mask;
        const float ar = lds[SRE + col * 17 + ua], ai = lds[SIM + col * 17 + ua];
        const float br = lds[SRE + col * 17 + ub], bi = lds[SIM + col * 17 + ub];
        __syncthreads();
        float nr, ni;
        if (u & mask) { nr = sh * ar + ch * br; ni = sh * ai + ch * bi; }
        else          { nr = ch * ar - sh * br; ni = ch * ai - sh * bi; }
        float rr, ri;
        if (u & mask) { rr = ch2 * nr - sh2 * ni; ri = ch2 * ni + sh2 * nr; }
        else          { rr = ch2 * nr + sh2 * ni; ri = ch2 * ni - sh2 * nr; }
        lds[SRE + col * 17 + u] = rr; lds[SIM + col * 17 + u] = ri;
        __syncthreads();
      }
      // CNOT ring (0,1)(1,2)(2,3)(3,0) as one permutation
      int src = u;
      if (src & 1) src ^= 8;
      if (src & 2) src ^= 1;
      if (src & 4) src ^= 2;
      if (src & 8) src ^= 4;
      const float pr = lds[SRE + col * 17 + src], pi = lds[SIM + col * 17 + src];
      __syncthreads();
      lds[SRE + col * 17 + u] = pr; lds[SIM + col * 17 + u] = pi;
      __syncthreads();
    }

    // M[w][s][t] = sum_u z_w(u) * Re(conj(U[u,s]) U[u,t])
#pragma unroll
    for (int k = 0; k < 4; ++k) {
      const int idx = tid + 256 * k;
      const int w = idx >> 8, s = (idx >> 4) & 15, t = idx & 15;
      const int mask = 8 >> w;
      float acc = 0.0f;
#pragma unroll
      for (int uu = 0; uu < 16; ++uu) {
        const float z = (uu & mask) ? -1.0f : 1.0f;
        acc += z * (lds[SRE + s * 17 + uu] * lds[SRE + t * 17 + uu] +
                    lds[SIM + s * 17 + uu] * lds[SIM + t * 17 + uu]);
      }
      lds[MOF + ((w * 16 + s) * 16 + t)] = acc;
    }
    __syncthreads();

    // A[pq][w]: 16-term sparse Pauli contraction (strided loop: 324 > 256!)
    for (int idx = tid; idx < 324; idx += 256) {
      const int w = idx & 3, pq = idx >> 2;
      const int p = pq / 9, qq = pq % 9;
      const int i0 = p / 3, i1 = p % 3, i2 = qq / 3, i3 = qq % 3;
      float acc = 0.0f;
#pragma unroll
      for (int comb = 0; comb < 16; ++comb) {
        int s = 0, t = 0;
        float coef = 0.0625f;
        int j;
        j = (comb >> 3) & 1; s |= j << 3; t |= ((i0 == 2) ? (j ^ 1) : j) << 3; if (i0 == 1 && j) coef = -coef;
        j = (comb >> 2) & 1; s |= j << 2; t |= ((i1 == 2) ? (j ^ 1) : j) << 2; if (i1 == 1 && j) coef = -coef;
        j = (comb >> 1) & 1; s |= j << 1; t |= ((i2 == 2) ? (j ^ 1) : j) << 1; if (i2 == 1 && j) coef = -coef;
        j = comb & 1;        s |= j;      t |= ((i3 == 2) ? (j ^ 1) : j);      if (i3 == 1 && j) coef = -coef;
        acc = fmaf(coef, lds[MOF + ((w * 16 + s) * 16 + t)], acc);
      }
      lds[AOF + idx] = acc;
    }
    __syncthreads();   // LAST barrier in the kernel
  }

  // ---- W fragment: lane's 4 features x 4 outputs = 16 VGPRs ----
  const float4* W4 = reinterpret_cast<const float4*>(Wp);
  const float4 w0 = W4[0 * 16 + f4];
  const float4 w1 = W4[1 * 16 + f4];
  const float4 w2 = W4[2 * 16 + f4];
  const float4 w3 = W4[3 * 16 + f4];

  float sa0 = 0.f, sa1 = 0.f, sa2 = 0.f, sa3 = 0.f;   // owned row's angles

  // COMP: 16 fma partial dots, 16-lane xor all-reduce (DPP), keep if owner.
#define COMP(i, PV) {                                                        \
    float r0 = fmaf(PV.x, w0.x, fmaf(PV.y, w0.y,                             \
               fmaf(PV.z, w0.z, PV.w * w0.w)));                              \
    float r1 = fmaf(PV.x, w1.x, fmaf(PV.y, w1.y,                             \
               fmaf(PV.z, w1.z, PV.w * w1.w)));                              \
    float r2 = fmaf(PV.x, w2.x, fmaf(PV.y, w2.y,                             \
               fmaf(PV.z, w2.z, PV.w * w2.w)));                              \
    float r3 = fmaf(PV.x, w3.x, fmaf(PV.y, w3.y,                             \
               fmaf(PV.z, w3.z, PV.w * w3.w)));                              \
    r0 += __shfl_xor(r0, 1, 64); r0 += __shfl_xor(r0, 2, 64);                \
    r0 += __shfl_xor(r0, 4, 64); r0 += __shfl_xor(r0, 8, 64);                \
    r1 += __shfl_xor(r1, 1, 64); r1 += __shfl_xor(r1, 2, 64);                \
    r1 += __shfl_xor(r1, 4, 64); r1 += __shfl_xor(r1, 8, 64);                \
    r2 += __shfl_xor(r2, 1, 64); r2 += __shfl_xor(r2, 2, 64);                \
    r2 += __shfl_xor(r2, 4, 64); r2 += __shfl_xor(r2, 8, 64);                \
    r3 += __shfl_xor(r3, 1, 64); r3 += __shfl_xor(r3, 2, 64);                \
    r3 += __shfl_xor(r3, 4, 64); r3 += __shfl_xor(r3, 8, 64);                \
    if (f4 == (i)) { sa0 = r0; sa1 = r1; sa2 = r2; sa3 = r3; }               \
  }

  // 16 iterations, 4-deep rotating prefetch, no barriers.
  COMP(0, p0);  p0 = xw[64 * 4];
  COMP(1, p1);  p1 = xw[64 * 5];
  COMP(2, p2);  p2 = xw[64 * 6];
  COMP(3, p3);  p3 = xw[64 * 7];
  COMP(4, p0);  p0 = xw[64 * 8];
  COMP(5, p1);  p1 = xw[64 * 9];
  COMP(6, p2);  p2 = xw[64 * 10];
  COMP(7, p3);  p3 = xw[64 * 11];
  COMP(8, p0);  p0 = xw[64 * 12];
  COMP(9, p1);  p1 = xw[64 * 13];
  COMP(10, p2); p2 = xw[64 * 14];
  COMP(11, p3); p3 = xw[64 * 15];
  COMP(12, p0);
  COMP(13, p1);
  COMP(14, p2);
  COMP(15, p3);
#undef COMP

  // ---- tail: each lane owns row (base + 4*f4 + q) ----
  // tanh(a) = 1 - 2/(e^{2a}+1)
  const float t0 = 1.0f - 2.0f / (__expf(2.0f * (sa0 + bp[0])) + 1.0f);
  const float t1 = 1.0f - 2.0f / (__expf(2.0f * (sa1 + bp[1])) + 1.0f);
  const float t2 = 1.0f - 2.0f / (__expf(2.0f * (sa2 + bp[2])) + 1.0f);
  const float t3 = 1.0f - 2.0f / (__expf(2.0f * (sa3 + bp[3])) + 1.0f);

  float c0, s0, c1, s1, c2, s2, c3, s3;
  __sincosf(t0, &s0, &c0); __sincosf(t1, &s1, &c1);
  __sincosf(t2, &s2, &c2); __sincosf(t3, &s3, &c3);

  const float g[9] = {1.f, c1, s1, c0, c0 * c1, c0 * s1, s0, s0 * c1, s0 * s1};
  const float h[9] = {1.f, c3, s3, c2, c2 * c3, c2 * s3, s2, s2 * c3, s2 * s3};

  float e0 = 0.f, e1 = 0.f, e2 = 0.f, e3 = 0.f;
#pragma unroll
  for (int p = 0; p < 9; ++p) {
#pragma unroll
    for (int qq = 0; qq < 9; ++qq) {
      const float4 a4 =
          *reinterpret_cast<const float4*>(&lds[AOF + (p * 9 + qq) * 4]);
      const float t = g[p] * h[qq];    // uniform-addr LDS broadcast
      e0 = fmaf(a4.x, t, e0); e1 = fmaf(a4.y, t, e1);
      e2 = fmaf(a4.z, t, e2); e3 = fmaf(a4.w, t, e3);
    }
  }
  reinterpret_cast<float4*>(out)[base + 4 * f4 + q] =
      make_float4(e0, e1, e2, e3);
}

extern "C" void kernel_launch(void* const* d_in, const int* in_sizes, int n_in,
                              void* d_out, int out_size, void* d_ws, size_t ws_size,
                              hipStream_t stream) {
  const float* x  = (const float*)d_in[0];
  const float* Wp = (const float*)d_in[1];
  const float* bp = (const float*)d_in[2];
  const float* qw = (const float*)d_in[3];
  float* out = (float*)d_out;
  (void)d_ws; (void)ws_size; (void)n_in; (void)out_size;

  const int B = in_sizes[0] / 64;           // 524288 rows
  qfused_kernel<<<B / 256, 256, 0, stream>>>(x, Wp, bp, qw, out);   // 2048 blocks
}

// Round 10
// 38.272 us; speedup vs baseline: 1.2669x; 1.2669x over previous
//
#include <hip/hip_runtime.h>
#include <cmath>

// Split design, round 10:
//   qprep (1 block): fixed-circuit 16x16 unitary -> A[81][4] into d_ws.
//   qmain (1024 blocks x 256): LDS-staged GEMV with raw lgkm-only barriers
//     (global prefetch NEVER drained by vmcnt(0)), 2-phase-deep ping-pong,
//     tail reads A via uniform s_load (SMEM pipe, K$) instead of LDS.
//
// Why: round-8 pipe audit -- tail's 81 ds_read_b128 = ~13us/CU of LDS pipe
// + staging ~11us, serialized against HBM (21.8us floor) by the vmcnt(0)
// inside __syncthreads. This moves the A-reads to the idle SMEM pipe and
// keeps loads in flight across barriers.

// ---- raw barrier: order LDS ops, do NOT drain global loads ----
#define BAR() asm volatile("s_waitcnt lgkmcnt(0)\n\ts_barrier" ::: "memory")

#define LOADX(R0, R1, R2, R3, P, C)                       \
  R0 = xb[((P) * 256 + 0 * 64) * 16 + (C) * 4];           \
  R1 = xb[((P) * 256 + 1 * 64) * 16 + (C) * 4];           \
  R2 = xb[((P) * 256 + 2 * 64) * 16 + (C) * 4];           \
  R3 = xb[((P) * 256 + 3 * 64) * 16 + (C) * 4];

#define STAGE(R0, R1, R2, R3)                                            \
  *reinterpret_cast<float4*>(&lds[(0 * 64 + rrow) * XS + q4w]) = R0;     \
  *reinterpret_cast<float4*>(&lds[(1 * 64 + rrow) * XS + q4w]) = R1;     \
  *reinterpret_cast<float4*>(&lds[(2 * 64 + rrow) * XS + q4w]) = R2;     \
  *reinterpret_cast<float4*>(&lds[(3 * 64 + rrow) * XS + q4w]) = R3;

#define GEMV(A0, A1, A2, A3, C) {                                          \
  const float4 xv0 = *reinterpret_cast<const float4*>(&lds[tid * XS + 0]); \
  const float4 xv1 = *reinterpret_cast<const float4*>(&lds[tid * XS + 4]); \
  const float4 xv2 = *reinterpret_cast<const float4*>(&lds[tid * XS + 8]); \
  const float4 xv3 = *reinterpret_cast<const float4*>(&lds[tid * XS + 12]);\
  const float xr[16] = {xv0.x, xv0.y, xv0.z, xv0.w, xv1.x, xv1.y, xv1.z,   \
                        xv1.w, xv2.x, xv2.y, xv2.z, xv2.w, xv3.x, xv3.y,   \
                        xv3.z, xv3.w};                                     \
  _Pragma("unroll")                                                        \
  for (int f = 0; f < 16; ++f) {                                          \
    A0 = fmaf(xr[f], Wp[(C) * 16 + f], A0);                                \
    A1 = fmaf(xr[f], Wp[64 + (C) * 16 + f], A1);                           \
    A2 = fmaf(xr[f], Wp[128 + (C) * 16 + f], A2);                          \
    A3 = fmaf(xr[f], Wp[192 + (C) * 16 + f], A3);                          \
  } }

// ---- prep kernel: verbatim round-2 structure (known correct) ----
__global__ __launch_bounds__(256) void qprep_kernel(
    const float* __restrict__ qw,   // [3][4][2]
    float* __restrict__ A_out)      // [81][4]
{
  __shared__ float sre[16][17];
  __shared__ float sim[16][17];
  __shared__ float M[4][16][16];
  const int tid = threadIdx.x;
  const int col = tid >> 4;
  const int u   = tid & 15;

  sre[col][u] = (u == col) ? 1.0f : 0.0f;
  sim[col][u] = 0.0f;
  __syncthreads();

#pragma unroll
  for (int l = 0; l < 3; ++l) {
#pragma unroll
    for (int w = 0; w < 4; ++w) {
      const int mask = 8 >> w;     // wire 0 = MSB
      float sh, ch, sh2, ch2;
      __sincosf(0.5f * qw[(l * 4 + w) * 2 + 0], &sh, &ch);    // RY
      __sincosf(0.5f * qw[(l * 4 + w) * 2 + 1], &sh2, &ch2);  // RZ
      const int ua = u & ~mask, ub = u | mask;
      const float ar = sre[col][ua], ai = sim[col][ua];
      const float br = sre[col][ub], bi = sim[col][ub];
      __syncthreads();
      float nr, ni;
      if (u & mask) { nr = sh * ar + ch * br; ni = sh * ai + ch * bi; }
      else          { nr = ch * ar - sh * br; ni = ch * ai - sh * bi; }
      float rr, ri;
      if (u & mask) { rr = ch2 * nr - sh2 * ni; ri = ch2 * ni + sh2 * nr; }
      else          { rr = ch2 * nr + sh2 * ni; ri = ch2 * ni - sh2 * nr; }
      sre[col][u] = rr; sim[col][u] = ri;
      __syncthreads();
    }
    int src = u;
    if (src & 1) src ^= 8;
    if (src & 2) src ^= 1;
    if (src & 4) src ^= 2;
    if (src & 8) src ^= 4;
    const float pr = sre[col][src], pi = sim[col][src];
    __syncthreads();
    sre[col][u] = pr; sim[col][u] = pi;
    __syncthreads();
  }

  for (int idx = tid; idx < 1024; idx += 256) {
    const int w = idx >> 8, s = (idx >> 4) & 15, t = idx & 15;
    const int mask = 8 >> w;
    float acc = 0.0f;
#pragma unroll
    for (int uu = 0; uu < 16; ++uu) {
      const float z = (uu & mask) ? -1.0f : 1.0f;
      acc += z * (sre[s][uu] * sre[t][uu] + sim[s][uu] * sim[t][uu]);
    }
    M[w >> 0][s][t] = acc;   // w in 0..3
  }
  __syncthreads();

  for (int idx = tid; idx < 324; idx += 256) {
    const int w = idx & 3, pq = idx >> 2;
    const int p = pq / 9, q = pq % 9;
    const int i0 = p / 3, i1 = p % 3, i2 = q / 3, i3 = q % 3;
    float acc = 0.0f;
#pragma unroll
    for (int comb = 0; comb < 16; ++comb) {
      int s = 0, t = 0;
      float coef = 0.0625f;
      int j;
      j = (comb >> 3) & 1; s |= j << 3; t |= ((i0 == 2) ? (j ^ 1) : j) << 3; if (i0 == 1 && j) coef = -coef;
      j = (comb >> 2) & 1; s |= j << 2; t |= ((i1 == 2) ? (j ^ 1) : j) << 2; if (i1 == 1 && j) coef = -coef;
      j = (comb >> 1) & 1; s |= j << 1; t |= ((i2 == 2) ? (j ^ 1) : j) << 1; if (i2 == 1 && j) coef = -coef;
      j = comb & 1;        s |= j;      t |= ((i3 == 2) ? (j ^ 1) : j);      if (i3 == 1 && j) coef = -coef;
      acc = fmaf(coef, M[w][s][t], acc);
    }
    A_out[idx] = acc;   // layout [pq*4 + w]
  }
}

// ---- main kernel ----
__global__ __launch_bounds__(256)
__attribute__((amdgpu_waves_per_eu(4, 4)))   // 128-VGPR budget: no spill
void qmain_kernel(
    const float* __restrict__ x,     // [B][64]
    const float* __restrict__ Wp,    // [4][64]
    const float* __restrict__ bp,    // [4]
    const float4* __restrict__ Aws,  // [81] float4 (from d_ws)
    float* __restrict__ out)         // [B][4]
{
  constexpr int XS = 20;             // xt word stride: 80B rows, 16B-aligned
  __shared__ alignas(16) float lds[256 * XS];   // 20 KB, staging only

  const int tid = threadIdx.x;
  const size_t row0 = (size_t)blockIdx.x * 512;
  const int rrow = tid >> 2;
  const int q4w  = (tid & 3) << 2;
  const float4* xb = reinterpret_cast<const float4*>(x) +
                     (row0 + (size_t)rrow) * 16 + (tid & 3);

  // 2-phase-deep prologue: chunks 0 and 1 in flight immediately
  float4 rbA0, rbA1, rbA2, rbA3, rbB0, rbB1, rbB2, rbB3;
  LOADX(rbA0, rbA1, rbA2, rbA3, 0, 0);
  LOADX(rbB0, rbB1, rbB2, rbB3, 0, 1);

  float aA0 = 0.f, aA1 = 0.f, aA2 = 0.f, aA3 = 0.f;
  float aB0 = 0.f, aB1 = 0.f, aB2 = 0.f, aB3 = 0.f;

  // 8 phases; stage chunk k, reload same buffer with chunk k+2.
  // Barriers are lgkm-only: prefetch loads stay in flight across them.
  STAGE(rbA0, rbA1, rbA2, rbA3); LOADX(rbA0, rbA1, rbA2, rbA3, 0, 2); BAR();
  GEMV(aA0, aA1, aA2, aA3, 0);   BAR();
  STAGE(rbB0, rbB1, rbB2, rbB3); LOADX(rbB0, rbB1, rbB2, rbB3, 0, 3); BAR();
  GEMV(aA0, aA1, aA2, aA3, 1);   BAR();
  STAGE(rbA0, rbA1, rbA2, rbA3); LOADX(rbA0, rbA1, rbA2, rbA3, 1, 0); BAR();
  GEMV(aA0, aA1, aA2, aA3, 2);   BAR();
  STAGE(rbB0, rbB1, rbB2, rbB3); LOADX(rbB0, rbB1, rbB2, rbB3, 1, 1); BAR();
  GEMV(aA0, aA1, aA2, aA3, 3);   BAR();
  STAGE(rbA0, rbA1, rbA2, rbA3); LOADX(rbA0, rbA1, rbA2, rbA3, 1, 2); BAR();
  GEMV(aB0, aB1, aB2, aB3, 0);   BAR();
  STAGE(rbB0, rbB1, rbB2, rbB3); LOADX(rbB0, rbB1, rbB2, rbB3, 1, 3); BAR();
  GEMV(aB0, aB1, aB2, aB3, 1);   BAR();
  STAGE(rbA0, rbA1, rbA2, rbA3); BAR();
  GEMV(aB0, aB1, aB2, aB3, 2);   BAR();
  STAGE(rbB0, rbB1, rbB2, rbB3); BAR();
  GEMV(aB0, aB1, aB2, aB3, 3);

  // ---- tail: tanh, sincos, g/h for both rows ----
  float g0[9], h0[9], g1[9], h1[9];
  {
    const float t0 = 1.0f - 2.0f / (__expf(2.0f * (aA0 + bp[0])) + 1.0f);
    const float t1 = 1.0f - 2.0f / (__expf(2.0f * (aA1 + bp[1])) + 1.0f);
    const float t2 = 1.0f - 2.0f / (__expf(2.0f * (aA2 + bp[2])) + 1.0f);
    const float t3 = 1.0f - 2.0f / (__expf(2.0f * (aA3 + bp[3])) + 1.0f);
    float c0, s0, c1, s1, c2, s2, c3, s3;
    __sincosf(t0, &s0, &c0); __sincosf(t1, &s1, &c1);
    __sincosf(t2, &s2, &c2); __sincosf(t3, &s3, &c3);
    g0[0] = 1.f; g0[1] = c1; g0[2] = s1; g0[3] = c0; g0[4] = c0 * c1;
    g0[5] = c0 * s1; g0[6] = s0; g0[7] = s0 * c1; g0[8] = s0 * s1;
    h0[0] = 1.f; h0[1] = c3; h0[2] = s3; h0[3] = c2; h0[4] = c2 * c3;
    h0[5] = c2 * s3; h0[6] = s2; h0[7] = s2 * c3; h0[8] = s2 * s3;
  }
  {
    const float t0 = 1.0f - 2.0f / (__expf(2.0f * (aB0 + bp[0])) + 1.0f);
    const float t1 = 1.0f - 2.0f / (__expf(2.0f * (aB1 + bp[1])) + 1.0f);
    const float t2 = 1.0f - 2.0f / (__expf(2.0f * (aB2 + bp[2])) + 1.0f);
    const float t3 = 1.0f - 2.0f / (__expf(2.0f * (aB3 + bp[3])) + 1.0f);
    float c0, s0, c1, s1, c2, s2, c3, s3;
    __sincosf(t0, &s0, &c0); __sincosf(t1, &s1, &c1);
    __sincosf(t2, &s2, &c2); __sincosf(t3, &s3, &c3);
    g1[0] = 1.f; g1[1] = c1; g1[2] = s1; g1[3] = c0; g1[4] = c0 * c1;
    g1[5] = c0 * s1; g1[6] = s0; g1[7] = s0 * c1; g1[8] = s0 * s1;
    h1[0] = 1.f; h1[1] = c3; h1[2] = s3; h1[3] = c2; h1[4] = c2 * c3;
    h1[5] = c2 * s3; h1[6] = s2; h1[7] = s2 * c3; h1[8] = s2 * s3;
  }

  // ---- contraction: A via uniform s_load (SMEM pipe), shared by 2 rows ----
  float e00 = 0.f, e01 = 0.f, e02 = 0.f, e03 = 0.f;
  float e10 = 0.f, e11 = 0.f, e12 = 0.f, e13 = 0.f;
#pragma unroll
  for (int p = 0; p < 9; ++p) {
#pragma unroll
    for (int q = 0; q < 9; ++q) {
      const float4 a4 = Aws[p * 9 + q];   // compile-time offset, uniform
      const float tA = g0[p] * h0[q];
      const float tB = g1[p] * h1[q];
      e00 = fmaf(a4.x, tA, e00); e01 = fmaf(a4.y, tA, e01);
      e02 = fmaf(a4.z, tA, e02); e03 = fmaf(a4.w, tA, e03);
      e10 = fmaf(a4.x, tB, e10); e11 = fmaf(a4.y, tB, e11);
      e12 = fmaf(a4.z, tB, e12); e13 = fmaf(a4.w, tB, e13);
    }
  }
  float4* out4 = reinterpret_cast<float4*>(out);
  out4[row0 + tid]       = make_float4(e00, e01, e02, e03);
  out4[row0 + 256 + tid] = make_float4(e10, e11, e12, e13);
}

extern "C" void kernel_launch(void* const* d_in, const int* in_sizes, int n_in,
                              void* d_out, int out_size, void* d_ws, size_t ws_size,
                              hipStream_t stream) {
  const float* x  = (const float*)d_in[0];
  const float* Wp = (const float*)d_in[1];
  const float* bp = (const float*)d_in[2];
  const float* qw = (const float*)d_in[3];
  float* out = (float*)d_out;
  float* A = (float*)d_ws;   // 324 floats
  (void)n_in; (void)out_size; (void)ws_size;

  qprep_kernel<<<1, 256, 0, stream>>>(qw, A);

  const int B = in_sizes[0] / 64;   // 524288
  qmain_kernel<<<B / 512, 256, 0, stream>>>(x, Wp, bp,
                                            (const float4*)A, out);
}

// Round 11
// 38.066 us; speedup vs baseline: 1.2738x; 1.0054x over previous
//
#include <hip/hip_runtime.h>
#include <cmath>

// Fused single kernel, round 11.
//
//   - Prep (A[81][4] from qweights via 16x16 unitary sim) runs per block in
//     LDS with lgkm-ONLY barriers: the 3-deep x prefetch issued before prep
//     stays in flight through all ~30 prep barriers (round-8's fused attempt
//     failed because __syncthreads drains vmcnt(0); round-10 proved the
//     lgkm-only barrier keeps loads live).
//   - Streaming: 8 chunk-phases, 3-buffer rotation (A,B,C), STAGE -> reload
//     same buffer 3 chunks ahead -> BAR -> GEMV -> BAR. Loads never drained.
//   - Tail: tanh/sincos + 81-term contraction vs LDS-resident A (uniform
//     b128 broadcasts), 2 rows/thread.

// lgkm-only barrier: orders LDS ops, does NOT drain global loads.
#define BAR() asm volatile("s_waitcnt lgkmcnt(0)\n\ts_barrier" ::: "memory")

#define LOADX(R0, R1, R2, R3, P, C)                       \
  R0 = xb[((P) * 256 + 0 * 64) * 16 + (C) * 4];           \
  R1 = xb[((P) * 256 + 1 * 64) * 16 + (C) * 4];           \
  R2 = xb[((P) * 256 + 2 * 64) * 16 + (C) * 4];           \
  R3 = xb[((P) * 256 + 3 * 64) * 16 + (C) * 4];

#define STAGE(R0, R1, R2, R3)                                            \
  *reinterpret_cast<float4*>(&lds[(0 * 64 + rrow) * XS + q4w]) = R0;     \
  *reinterpret_cast<float4*>(&lds[(1 * 64 + rrow) * XS + q4w]) = R1;     \
  *reinterpret_cast<float4*>(&lds[(2 * 64 + rrow) * XS + q4w]) = R2;     \
  *reinterpret_cast<float4*>(&lds[(3 * 64 + rrow) * XS + q4w]) = R3;

#define GEMV(A0, A1, A2, A3, C) {                                          \
  const float4 xv0 = *reinterpret_cast<const float4*>(&lds[tid * XS + 0]); \
  const float4 xv1 = *reinterpret_cast<const float4*>(&lds[tid * XS + 4]); \
  const float4 xv2 = *reinterpret_cast<const float4*>(&lds[tid * XS + 8]); \
  const float4 xv3 = *reinterpret_cast<const float4*>(&lds[tid * XS + 12]);\
  const float xr[16] = {xv0.x, xv0.y, xv0.z, xv0.w, xv1.x, xv1.y, xv1.z,   \
                        xv1.w, xv2.x, xv2.y, xv2.z, xv2.w, xv3.x, xv3.y,   \
                        xv3.z, xv3.w};                                     \
  _Pragma("unroll")                                                        \
  for (int f = 0; f < 16; ++f) {                                          \
    A0 = fmaf(xr[f], Wp[(C) * 16 + f], A0);                                \
    A1 = fmaf(xr[f], Wp[64 + (C) * 16 + f], A1);                           \
    A2 = fmaf(xr[f], Wp[128 + (C) * 16 + f], A2);                          \
    A3 = fmaf(xr[f], Wp[192 + (C) * 16 + f], A3);                          \
  } }

__global__ __launch_bounds__(256)
__attribute__((amdgpu_waves_per_eu(4, 4)))   // 128-VGPR budget: no spill
void qfused_kernel(
    const float* __restrict__ x,    // [B][64]
    const float* __restrict__ Wp,   // [4][64]
    const float* __restrict__ bp,   // [4]
    const float* __restrict__ qw,   // [3][4][2]
    float* __restrict__ out)        // [B][4]
{
  constexpr int XS  = 20;           // staging stride: 80B rows, 16B-aligned
  constexpr int AOF = 256 * XS;     // A[324] past the staging region
  __shared__ alignas(16) float lds[256 * XS + 324];   // 21.8 KB
  constexpr int SRE = 0;            // prep scratch inside staging region
  constexpr int SIM = 272;
  constexpr int MOF = 544;

  const int tid = threadIdx.x;
  const size_t row0 = (size_t)blockIdx.x * 512;
  const int rrow = tid >> 2;
  const int q4w  = (tid & 3) << 2;
  const float4* xb = reinterpret_cast<const float4*>(x) +
                     (row0 + (size_t)rrow) * 16 + (tid & 3);

  // ---- 3-deep prefetch (chunks 0,1,2): in flight through ALL of prep ----
  float4 rA0, rA1, rA2, rA3, rB0, rB1, rB2, rB3, rC0, rC1, rC2, rC3;
  LOADX(rA0, rA1, rA2, rA3, 0, 0);
  LOADX(rB0, rB1, rB2, rB3, 0, 1);
  LOADX(rC0, rC1, rC2, rC3, 0, 2);

  // ---- prep: A[81][4] at lds[AOF]; lgkm-only barriers throughout ----
  {
    const int col = tid >> 4;
    const int u   = tid & 15;
    lds[SRE + col * 17 + u] = (u == col) ? 1.0f : 0.0f;
    lds[SIM + col * 17 + u] = 0.0f;
    BAR();

#pragma unroll
    for (int l = 0; l < 3; ++l) {
#pragma unroll
      for (int w = 0; w < 4; ++w) {
        const int mask = 8 >> w;     // wire 0 = MSB
        float sh, ch, sh2, ch2;
        __sincosf(0.5f * qw[(l * 4 + w) * 2 + 0], &sh, &ch);    // RY
        __sincosf(0.5f * qw[(l * 4 + w) * 2 + 1], &sh2, &ch2);  // RZ
        const int ua = u & ~mask, ub = u | mask;
        const float ar = lds[SRE + col * 17 + ua], ai = lds[SIM + col * 17 + ua];
        const float br = lds[SRE + col * 17 + ub], bi = lds[SIM + col * 17 + ub];
        BAR();
        float nr, ni;
        if (u & mask) { nr = sh * ar + ch * br; ni = sh * ai + ch * bi; }
        else          { nr = ch * ar - sh * br; ni = ch * ai - sh * bi; }
        float rr, ri;
        if (u & mask) { rr = ch2 * nr - sh2 * ni; ri = ch2 * ni + sh2 * nr; }
        else          { rr = ch2 * nr + sh2 * ni; ri = ch2 * ni - sh2 * nr; }
        lds[SRE + col * 17 + u] = rr; lds[SIM + col * 17 + u] = ri;
        BAR();
      }
      // CNOT ring (0,1)(1,2)(2,3)(3,0) as one permutation
      int src = u;
      if (src & 1) src ^= 8;
      if (src & 2) src ^= 1;
      if (src & 4) src ^= 2;
      if (src & 8) src ^= 4;
      const float pr = lds[SRE + col * 17 + src], pi = lds[SIM + col * 17 + src];
      BAR();
      lds[SRE + col * 17 + u] = pr; lds[SIM + col * 17 + u] = pi;
      BAR();
    }

    // M[w][s][t] = sum_u z_w(u) * Re(conj(U[u,s]) U[u,t])
#pragma unroll
    for (int k = 0; k < 4; ++k) {
      const int idx = tid + 256 * k;
      const int w = idx >> 8, s = (idx >> 4) & 15, t = idx & 15;
      const int mask = 8 >> w;
      float acc = 0.0f;
#pragma unroll
      for (int uu = 0; uu < 16; ++uu) {
        const float z = (uu & mask) ? -1.0f : 1.0f;
        acc += z * (lds[SRE + s * 17 + uu] * lds[SRE + t * 17 + uu] +
                    lds[SIM + s * 17 + uu] * lds[SIM + t * 17 + uu]);
      }
      lds[MOF + ((w * 16 + s) * 16 + t)] = acc;
    }
    BAR();

    // A[pq][w]: 16-term sparse Pauli contraction (strided: 324 > 256!)
    for (int idx = tid; idx < 324; idx += 256) {
      const int w = idx & 3, pq = idx >> 2;
      const int p = pq / 9, q = pq % 9;
      const int i0 = p / 3, i1 = p % 3, i2 = q / 3, i3 = q % 3;
      float acc = 0.0f;
#pragma unroll
      for (int comb = 0; comb < 16; ++comb) {
        int s = 0, t = 0;
        float coef = 0.0625f;
        int j;
        j = (comb >> 3) & 1; s |= j << 3; t |= ((i0 == 2) ? (j ^ 1) : j) << 3; if (i0 == 1 && j) coef = -coef;
        j = (comb >> 2) & 1; s |= j << 2; t |= ((i1 == 2) ? (j ^ 1) : j) << 2; if (i1 == 1 && j) coef = -coef;
        j = (comb >> 1) & 1; s |= j << 1; t |= ((i2 == 2) ? (j ^ 1) : j) << 1; if (i2 == 1 && j) coef = -coef;
        j = comb & 1;        s |= j;      t |= ((i3 == 2) ? (j ^ 1) : j);      if (i3 == 1 && j) coef = -coef;
        acc = fmaf(coef, lds[MOF + ((w * 16 + s) * 16 + t)], acc);
      }
      lds[AOF + idx] = acc;
    }
    BAR();   // A ready; staging region free
  }

  // ---- 8 chunk-phases, 3-buffer rotation, never drain vmcnt ----
  float aA0 = 0.f, aA1 = 0.f, aA2 = 0.f, aA3 = 0.f;
  float aB0 = 0.f, aB1 = 0.f, aB2 = 0.f, aB3 = 0.f;

  STAGE(rA0, rA1, rA2, rA3); LOADX(rA0, rA1, rA2, rA3, 0, 3); BAR();
  GEMV(aA0, aA1, aA2, aA3, 0); BAR();
  STAGE(rB0, rB1, rB2, rB3); LOADX(rB0, rB1, rB2, rB3, 1, 0); BAR();
  GEMV(aA0, aA1, aA2, aA3, 1); BAR();
  STAGE(rC0, rC1, rC2, rC3); LOADX(rC0, rC1, rC2, rC3, 1, 1); BAR();
  GEMV(aA0, aA1, aA2, aA3, 2); BAR();
  STAGE(rA0, rA1, rA2, rA3); LOADX(rA0, rA1, rA2, rA3, 1, 2); BAR();
  GEMV(aA0, aA1, aA2, aA3, 3); BAR();
  STAGE(rB0, rB1, rB2, rB3); LOADX(rB0, rB1, rB2, rB3, 1, 3); BAR();
  GEMV(aB0, aB1, aB2, aB3, 0); BAR();
  STAGE(rC0, rC1, rC2, rC3); BAR();
  GEMV(aB0, aB1, aB2, aB3, 1); BAR();
  STAGE(rA0, rA1, rA2, rA3); BAR();
  GEMV(aB0, aB1, aB2, aB3, 2); BAR();
  STAGE(rB0, rB1, rB2, rB3); BAR();
  GEMV(aB0, aB1, aB2, aB3, 3);

  // ---- tail: tanh, sincos, g/h for both rows ----
  float g0[9], h0[9], g1[9], h1[9];
  {
    const float t0 = 1.0f - 2.0f / (__expf(2.0f * (aA0 + bp[0])) + 1.0f);
    const float t1 = 1.0f - 2.0f / (__expf(2.0f * (aA1 + bp[1])) + 1.0f);
    const float t2 = 1.0f - 2.0f / (__expf(2.0f * (aA2 + bp[2])) + 1.0f);
    const float t3 = 1.0f - 2.0f / (__expf(2.0f * (aA3 + bp[3])) + 1.0f);
    float c0, s0, c1, s1, c2, s2, c3, s3;
    __sincosf(t0, &s0, &c0); __sincosf(t1, &s1, &c1);
    __sincosf(t2, &s2, &c2); __sincosf(t3, &s3, &c3);
    g0[0] = 1.f; g0[1] = c1; g0[2] = s1; g0[3] = c0; g0[4] = c0 * c1;
    g0[5] = c0 * s1; g0[6] = s0; g0[7] = s0 * c1; g0[8] = s0 * s1;
    h0[0] = 1.f; h0[1] = c3; h0[2] = s3; h0[3] = c2; h0[4] = c2 * c3;
    h0[5] = c2 * s3; h0[6] = s2; h0[7] = s2 * c3; h0[8] = s2 * s3;
  }
  {
    const float t0 = 1.0f - 2.0f / (__expf(2.0f * (aB0 + bp[0])) + 1.0f);
    const float t1 = 1.0f - 2.0f / (__expf(2.0f * (aB1 + bp[1])) + 1.0f);
    const float t2 = 1.0f - 2.0f / (__expf(2.0f * (aB2 + bp[2])) + 1.0f);
    const float t3 = 1.0f - 2.0f / (__expf(2.0f * (aB3 + bp[3])) + 1.0f);
    float c0, s0, c1, s1, c2, s2, c3, s3;
    __sincosf(t0, &s0, &c0); __sincosf(t1, &s1, &c1);
    __sincosf(t2, &s2, &c2); __sincosf(t3, &s3, &c3);
    g1[0] = 1.f; g1[1] = c1; g1[2] = s1; g1[3] = c0; g1[4] = c0 * c1;
    g1[5] = c0 * s1; g1[6] = s0; g1[7] = s0 * c1; g1[8] = s0 * s1;
    h1[0] = 1.f; h1[1] = c3; h1[2] = s3; h1[3] = c2; h1[4] = c2 * c3;
    h1[5] = c2 * s3; h1[6] = s2; h1[7] = s2 * c3; h1[8] = s2 * s3;
  }

  // ---- contraction: 81 uniform b128 LDS broadcasts shared by 2 rows ----
  float e00 = 0.f, e01 = 0.f, e02 = 0.f, e03 = 0.f;
  float e10 = 0.f, e11 = 0.f, e12 = 0.f, e13 = 0.f;
#pragma unroll
  for (int p = 0; p < 9; ++p) {
#pragma unroll
    for (int q = 0; q < 9; ++q) {
      const float4 a4 =
          *reinterpret_cast<const float4*>(&lds[AOF + (p * 9 + q) * 4]);
      const float tA = g0[p] * h0[q];
      const float tB = g1[p] * h1[q];
      e00 = fmaf(a4.x, tA, e00); e01 = fmaf(a4.y, tA, e01);
      e02 = fmaf(a4.z, tA, e02); e03 = fmaf(a4.w, tA, e03);
      e10 = fmaf(a4.x, tB, e10); e11 = fmaf(a4.y, tB, e11);
      e12 = fmaf(a4.z, tB, e12); e13 = fmaf(a4.w, tB, e13);
    }
  }
  float4* out4 = reinterpret_cast<float4*>(out);
  out4[row0 + tid]       = make_float4(e00, e01, e02, e03);
  out4[row0 + 256 + tid] = make_float4(e10, e11, e12, e13);
}

extern "C" void kernel_launch(void* const* d_in, const int* in_sizes, int n_in,
                              void* d_out, int out_size, void* d_ws, size_t ws_size,
                              hipStream_t stream) {
  const float* x  = (const float*)d_in[0];
  const float* Wp = (const float*)d_in[1];
  const float* bp = (const float*)d_in[2];
  const float* qw = (const float*)d_in[3];
  float* out = (float*)d_out;
  (void)d_ws; (void)ws_size; (void)n_in; (void)out_size;

  const int B = in_sizes[0] / 64;   // 524288
  qfused_kernel<<<B / 512, 256, 0, stream>>>(x, Wp, bp, qw, out);
}